// Round 10
// baseline (100.706 us; speedup 1.0000x reference)
//
#include <hip/hip_runtime.h>
#include <hip/hip_bf16.h>

#define D_MODEL 512
#define D_STATE 32
#define BATCH 8
#define SEQ 4096
#define MROWS (BATCH * SEQ)
#define NBLK 1024

typedef __bf16 bf16;
typedef __bf16 bf16x4 __attribute__((ext_vector_type(4)));
typedef __bf16 bf16x8 __attribute__((ext_vector_type(8)));
typedef float f32x4 __attribute__((ext_vector_type(4)));

#define CHUNK 16
#define BURN 80
#define NCHUNK (SEQ / CHUNK)   // 256 chunks per batch, 2048 chains

__device__ __forceinline__ bf16x8 cvt8(const f32x4 a, const f32x4 b) {
  bf16x8 h;
  h[0] = (bf16)a[0]; h[1] = (bf16)a[1]; h[2] = (bf16)a[2]; h[3] = (bf16)a[3];
  h[4] = (bf16)b[0]; h[5] = (bf16)b[1]; h[6] = (bf16)b[2]; h[7] = (bf16)b[3];
  return h;
}

// ================= k_A: block-local, LDS-free MFMA loop =================
// Per block (32 rows): dt-reduce -> X=(I-.5dtA)^-1 (wave0, overlapped) ->
// s_raw = x@B^T via MFMA with operands loaded DIRECTLY from global in fragment
// order (x converted->xb on the fly; B hi/lo split in registers; B is L2-resident)
// -> LDS transpose -> rotated-bank X matvec -> uB. Block 0 writes A_bar.
__global__ __launch_bounds__(256, 4) void k_A(
    const float* __restrict__ x, const float* __restrict__ A, const float* __restrict__ B,
    const float* __restrict__ C, const float* __restrict__ Dv, const float* __restrict__ log_dt,
    const float* __restrict__ W,
    float* __restrict__ A_bar, bf16* __restrict__ CW, bf16* __restrict__ WD,
    float* __restrict__ uB, bf16* __restrict__ xb) {
  __shared__ float Xs[32][32];      // dt scratch -> M -> X
  __shared__ float srw[32 * 33];    // s_raw transpose buffer (padded)
  const int bid = blockIdx.x, t = threadIdx.x;
  const int w = t >> 6, lane = t & 63;
  const int l15 = lane & 15, kg = lane >> 4;
  float* Xf = &Xs[0][0];
  const long rowbase = (long)bid * 32;

  // ---- dt partials + tree reduce ----
  {
    float v0 = __expf(log_dt[t]);
    float v1 = __expf(log_dt[t + 256]);
    v0 = fminf(fmaxf(v0, 1e-4f), 1.0f);
    v1 = fminf(fmaxf(v1, 1e-4f), 1.0f);
    Xf[t] = v0 + v1;
  }
  __syncthreads();
  for (int s2 = 128; s2 > 0; s2 >>= 1) {
    if (t < s2) Xf[t] += Xf[t + s2];
    __syncthreads();
  }
  const float dtv = Xf[0] * (1.0f / 512.0f);
  __syncthreads();
  // ---- stage M = I - 0.5dt*A ----
  {
    const int i0 = 4 * t;
    const f32x4 av = *(const f32x4*)(A + i0);
    f32x4 mv;
#pragma unroll
    for (int q = 0; q < 4; q++) {
      const int r = (i0 + q) >> 5, c = (i0 + q) & 31;
      mv[q] = (r == c ? 1.0f : 0.0f) - 0.5f * dtv * av[q];
    }
    *(f32x4*)(Xf + i0) = mv;
  }
  __syncthreads();
  // ---- wave 0: forward substitution X = M^{-1} (in-wave lockstep; other waves
  //      proceed straight into the barrier-free MFMA loop below) ----
  if (t < 32) {
    const int j = t;
    float xcol[32];
#pragma unroll
    for (int i = 0; i < 32; i++) {
      float s0 = 0.f, s1 = 0.f, s2 = 0.f, s3 = 0.f;
#pragma unroll
      for (int k = 0; k < 32; k += 4) {
        if (k < i)     s0 -= Xf[i * 32 + k]     * xcol[k];
        if (k + 1 < i) s1 -= Xf[i * 32 + k + 1] * xcol[k + 1];
        if (k + 2 < i) s2 -= Xf[i * 32 + k + 2] * xcol[k + 2];
        if (k + 3 < i) s3 -= Xf[i * 32 + k + 3] * xcol[k + 3];
      }
      const float num = (i == j ? 1.0f : 0.0f) + ((s0 + s1) + (s2 + s3));
      xcol[i] = (i >= j) ? num / Xf[i * 32 + i] : 0.0f;
    }
#pragma unroll
    for (int i = 0; i < 32; i++) Xs[i][j] = xcol[i];   // bank j per lane: conflict-free
  }

  // ---- s_raw = x @ B^T : no LDS, no barriers; operands in fragment order ----
  const int m = w & 1, nf = w >> 1;
  const int arow = m * 16 + l15;
  const int brow = nf * 16 + l15;
  f32x4 acc = (f32x4)(0.0f);
  {
    const float* xp = x + (rowbase + arow) * D_MODEL + kg * 8;
    bf16* xo = xb + (rowbase + arow) * D_MODEL + kg * 8;
    const float* bp = B + brow * D_MODEL + kg * 8;
#pragma unroll
    for (int kt = 0; kt < 16; kt++) {
      const f32x4 xa = *(const f32x4*)(xp + kt * 32);
      const f32x4 xc = *(const f32x4*)(xp + kt * 32 + 4);
      const bf16x8 af = cvt8(xa, xc);
      if (nf == 0) *(bf16x8*)(xo + kt * 32) = af;      // waves 0,1 cover rows 0..31
      const f32x4 b0 = *(const f32x4*)(bp + kt * 32);
      const f32x4 b1 = *(const f32x4*)(bp + kt * 32 + 4);
      const bf16x8 bh = cvt8(b0, b1);
      bf16x8 bl;
#pragma unroll
      for (int q = 0; q < 4; q++) {
        bl[q]     = (bf16)(b0[q] - (float)bh[q]);
        bl[q + 4] = (bf16)(b1[q] - (float)bh[q + 4]);
      }
      acc = __builtin_amdgcn_mfma_f32_16x16x32_bf16(af, bh, acc, 0, 0, 0);
      acc = __builtin_amdgcn_mfma_f32_16x16x32_bf16(af, bl, acc, 0, 0, 0);
    }
  }
  __syncthreads();   // X complete + all acc ready
  // ---- block 0 only: A_bar = (I + 0.5dt*A) @ X ----
  if (bid == 0) {
    const int i0 = 4 * t;
    const int r = t >> 3;
    f32x4 ov;
#pragma unroll
    for (int q = 0; q < 4; q++) {
      const int c = (i0 + q) & 31;
      float s = 0.f;
#pragma unroll
      for (int k = 0; k < 32; k++) {
        const float p2 = (r == k ? 1.0f : 0.0f) + 0.5f * dtv * A[r * 32 + k];
        s = fmaf(p2, Xf[k * 32 + c], s);
      }
      ov[q] = s;
    }
    *(f32x4*)(A_bar + i0) = ov;
  }
  // ---- s_raw to LDS: srw[row][col], C/D layout col=l15(+nf*16), row=kg*4+reg(+m*16) ----
  {
    const int col = nf * 16 + l15;
#pragma unroll
    for (int jj = 0; jj < 4; jj++)
      srw[(m * 16 + kg * 4 + jj) * 33 + col] = acc[jj];
  }
  __syncthreads();
  // ---- uB[row][n] = dt * sum_k X[n][k] * s_raw[row][k]  (rotated k: conflict-free) ----
  {
    const int n = t & 31, r0 = t >> 5;
    float u0 = 0.f, u1 = 0.f, u2 = 0.f, u3 = 0.f;
#pragma unroll
    for (int k2 = 0; k2 < 32; k2++) {
      const int k = (k2 + n) & 31;
      const float xv = Xf[n * 32 + k];
      u0 = fmaf(xv, srw[(r0)      * 33 + k], u0);
      u1 = fmaf(xv, srw[(r0 + 8)  * 33 + k], u1);
      u2 = fmaf(xv, srw[(r0 + 16) * 33 + k], u2);
      u3 = fmaf(xv, srw[(r0 + 24) * 33 + k], u3);
    }
    float* up = uB + (rowbase + r0) * D_STATE + n;
    up[0]            = dtv * u0;
    up[8 * D_STATE]  = dtv * u1;
    up[16 * D_STATE] = dtv * u2;
    up[24 * D_STATE] = dtv * u3;
  }
  // ---- side jobs: CW (blocks 1..64), WD (65..80) ----
  if (bid >= 1 && bid <= 64) {
    const int idx = (bid - 1) * 256 + t;
    const int e = idx >> 5, n = idx & 31;
    float s = 0.f;
    for (int d = 0; d < D_MODEL; d += 4) {
      const f32x4 wv = *(const f32x4*)(W + e * D_MODEL + d);
      s = fmaf(wv[0], C[(d + 0) * D_STATE + n], s);
      s = fmaf(wv[1], C[(d + 1) * D_STATE + n], s);
      s = fmaf(wv[2], C[(d + 2) * D_STATE + n], s);
      s = fmaf(wv[3], C[(d + 3) * D_STATE + n], s);
    }
    CW[idx] = (bf16)s;
  } else if (bid >= 65 && bid <= 80) {
#pragma unroll
    for (int jj = 0; jj < 16; jj++) {
      const int i = (bid - 65) * 16384 + jj * 1024 + t * 4;
      const f32x4 wv = *(const f32x4*)(W + i);
      const f32x4 dv = *(const f32x4*)(Dv + (i & 511));
      bf16x4 h;
#pragma unroll
      for (int q = 0; q < 4; q++) h[q] = (bf16)(wv[q] * dv[q]);
      *(bf16x4*)(WD + i) = h;
    }
  }
}

// ---------------- k_scan: standalone; a[] pinned in VGPRs (no remat/reload) ----------------
__global__ void k_scan(const float* __restrict__ uB, const float* __restrict__ A_bar,
                       bf16* __restrict__ Sb, float* __restrict__ fs) {
  __shared__ float sbuf[256];         // 8 groups x 32 state elems
  const int t = threadIdx.x;
  const int g = t >> 5, n = t & 31;
  const int chain = blockIdx.x * 8 + g;
  const int b = chain >> 8;           // 256 chunks per batch
  const int ch = chain & 255;
  const int cs = ch * CHUNK;
  const int t0 = cs - BURN;           // may be negative (u treated as 0 there)
  const int ce = cs + CHUNK;

  float a[32];
#pragma unroll
  for (int k = 0; k < 32; k += 4) {
    const f32x4 v = *(const f32x4*)(A_bar + n * 32 + k);
    a[k] = v[0]; a[k + 1] = v[1]; a[k + 2] = v[2]; a[k + 3] = v[3];
  }
#pragma unroll
  for (int k = 0; k < 32; k++) asm volatile("" : "+v"(a[k]));

  const float* ub = uB + (long)b * SEQ * D_STATE + n;
  bf16* sp = Sb + ((long)b * SEQ + cs) * D_STATE + n;
  float* myslot = &sbuf[g * 32];

  float s = 0.f;
  float ubuf[8], unext[8];
#pragma unroll
  for (int i = 0; i < 8; i++) {
    const int tt = t0 + i;
    ubuf[i] = (tt >= 0) ? ub[(long)tt * D_STATE] : 0.f;
  }
  for (int tg = t0; tg < ce; tg += 8) {
    const int tn = tg + 8;
#pragma unroll
    for (int i = 0; i < 8; i++) {
      const int tt = tn + i;
      unext[i] = (tt >= 0 && tt < ce) ? ub[(long)tt * D_STATE] : 0.f;
    }
#pragma unroll
    for (int i = 0; i < 8; i++) {
      const int tt = tg + i;
      myslot[n] = s;   // ds_write_b32, wave-ordered before the reads below
      const f32x4 s0 = *(const f32x4*)(myslot + 0);
      const f32x4 s1 = *(const f32x4*)(myslot + 4);
      const f32x4 s2 = *(const f32x4*)(myslot + 8);
      const f32x4 s3 = *(const f32x4*)(myslot + 12);
      const f32x4 s4 = *(const f32x4*)(myslot + 16);
      const f32x4 s5 = *(const f32x4*)(myslot + 20);
      const f32x4 s6 = *(const f32x4*)(myslot + 24);
      const f32x4 s7 = *(const f32x4*)(myslot + 28);
      float acc0 = ubuf[i], acc1 = 0.f, acc2 = 0.f, acc3 = 0.f;
#pragma unroll
      for (int q = 0; q < 4; q++) {
        acc0 = fmaf(a[0 + q],  s0[q], acc0);
        acc1 = fmaf(a[4 + q],  s1[q], acc1);
        acc2 = fmaf(a[8 + q],  s2[q], acc2);
        acc3 = fmaf(a[12 + q], s3[q], acc3);
        acc0 = fmaf(a[16 + q], s4[q], acc0);
        acc1 = fmaf(a[20 + q], s5[q], acc1);
        acc2 = fmaf(a[24 + q], s6[q], acc2);
        acc3 = fmaf(a[28 + q], s7[q], acc3);
      }
      const float z = (acc0 + acc1) + (acc2 + acc3);
      const float e = __expf(2.f * z);
      const float r = __builtin_amdgcn_rcpf(e + 1.f);
      s = fmaf(-2.f, r, 1.f);
      if (tt >= cs) sp[(long)(tt - cs) * D_STATE] = (bf16)s;
    }
#pragma unroll
    for (int i = 0; i < 8; i++) ubuf[i] = unext[i];
  }
  if (ch == NCHUNK - 1) fs[b * D_STATE + n] = s;
}

// ---------------- k_out: out = S@CW^T + xb@WD^T + b (bf16 MFMA, 128x128 tile) ----------------
__device__ __forceinline__ void stage_tile(const void* gbase, long row0, long rowStrideB,
                                           int kByte, void* lds, int w, int lane) {
#pragma unroll
  for (int j = 0; j < 2; j++) {
    const int base_off = (w << 11) + (j << 10);
    const int boff = base_off + (lane << 4);
    const int r = boff >> 6;
    const int s = (boff >> 4) & 3;
    const int cb = ((s ^ (r & 3)) << 4);
    const char* src = (const char*)gbase + (row0 + r) * rowStrideB + kByte + cb;
    __builtin_amdgcn_global_load_lds(
        (const __attribute__((address_space(1))) void*)src,
        (__attribute__((address_space(3))) void*)((char*)lds + base_off), 16, 0, 0);
  }
}

__global__ __launch_bounds__(256) void k_out(const bf16* __restrict__ xb,
                                             const bf16* __restrict__ WD,
                                             const bf16* __restrict__ Sb,
                                             const bf16* __restrict__ CW,
                                             const float* __restrict__ bias,
                                             float* __restrict__ out) {
  __shared__ bf16 As[2][128 * 32];
  __shared__ bf16 Bs[2][128 * 32];
  const int tid = threadIdx.x;
  const int w = tid >> 6, lane = tid & 63;
  const int swz = (blockIdx.x & 7) * 128 + (blockIdx.x >> 3);
  const int bm = swz >> 2, bn = swz & 3;
  const long rowbase = (long)bm * 128;
  const long colbase = (long)bn * 128;
  const int wr = w >> 1, wc = w & 1;
  const int l15 = lane & 15, kg = lane >> 4;
  const int kgs = kg ^ (l15 & 3);

  f32x4 acc[4][4];
#pragma unroll
  for (int m = 0; m < 4; m++)
#pragma unroll
    for (int n = 0; n < 4; n++) acc[m][n] = (f32x4)(0.0f);

  const int aoff = (wr * 64 + l15) * 32 + kgs * 8;
  const int boff = (wc * 64 + l15) * 32 + kgs * 8;

  auto STAGE = [&](int ti, int b) {
    if (ti < 16) {
      stage_tile(xb, rowbase, 1024, ti * 64, &As[b][0], w, lane);
      stage_tile(WD, colbase, 1024, ti * 64, &Bs[b][0], w, lane);
    } else {
      stage_tile(Sb, rowbase, 64, 0, &As[b][0], w, lane);
      stage_tile(CW, colbase, 64, 0, &Bs[b][0], w, lane);
    }
  };

  STAGE(0, 0);
  __syncthreads();
#pragma unroll 1
  for (int kt = 0; kt < 17; kt++) {
    const int cur = kt & 1;
    if (kt < 16) STAGE(kt + 1, cur ^ 1);
    bf16x8 af[4], bfr[4];
#pragma unroll
    for (int m = 0; m < 4; m++) af[m] = *(const bf16x8*)&As[cur][aoff + m * 16 * 32];
#pragma unroll
    for (int n = 0; n < 4; n++) bfr[n] = *(const bf16x8*)&Bs[cur][boff + n * 16 * 32];
#pragma unroll
    for (int m = 0; m < 4; m++)
#pragma unroll
      for (int n = 0; n < 4; n++)
        acc[m][n] = __builtin_amdgcn_mfma_f32_16x16x32_bf16(af[m], bfr[n], acc[m][n], 0, 0, 0);
    __syncthreads();
  }
#pragma unroll
  for (int n = 0; n < 4; n++) {
    const int e = (int)colbase + wc * 64 + n * 16 + l15;
    const float bv = bias[e];
#pragma unroll
    for (int m = 0; m < 4; m++) {
      const long r0 = rowbase + wr * 64 + m * 16 + kg * 4;
      const f32x4 v = acc[m][n];
#pragma unroll
      for (int jj = 0; jj < 4; jj++) out[(r0 + jj) * (long)D_MODEL + e] = v[jj] + bv;
    }
  }
}

extern "C" void kernel_launch(void* const* d_in, const int* in_sizes, int n_in,
                              void* d_out, int out_size, void* d_ws, size_t ws_size,
                              hipStream_t stream) {
  const float* x      = (const float*)d_in[0];
  const float* A      = (const float*)d_in[1];
  const float* B      = (const float*)d_in[2];
  const float* C      = (const float*)d_in[3];
  const float* Dv     = (const float*)d_in[4];
  const float* log_dt = (const float*)d_in[5];
  const float* W      = (const float*)d_in[6];
  const float* b_out  = (const float*)d_in[7];
  float* out = (float*)d_out;
  float* fs  = out + (long)MROWS * D_MODEL;  // final_state (8x32) after y

  char* ws = (char*)d_ws;
  float* A_bar = (float*)(ws + 0);                    // 4 KB
  bf16*  CW    = (bf16*)(ws + (68L << 10));           // 32 KB
  bf16*  WD    = (bf16*)(ws + (100L << 10));          // 512 KB
  bf16*  Sb    = (bf16*)(ws + (612L << 10));          // 2 MB
  float* uB    = (float*)(ws + (2660L << 10));        // 4 MB
  bf16*  xb    = (bf16*)(ws + (6756L << 10));         // 32 MB

  k_A<<<dim3(NBLK), dim3(256), 0, stream>>>(x, A, B, C, Dv, log_dt, W,
                                            A_bar, CW, WD, uB, xb);
  k_scan<<<dim3(256), dim3(256), 0, stream>>>(uB, A_bar, Sb, fs);
  k_out<<<dim3((MROWS / 128) * (D_MODEL / 128)), dim3(256), 0, stream>>>(xb, WD, Sb, CW, b_out, out);
}

// Round 11
// 95.628 us; speedup vs baseline: 1.0531x; 1.0531x over previous
//
#include <hip/hip_runtime.h>
#include <hip/hip_bf16.h>

#define D_MODEL 512
#define D_STATE 32
#define BATCH 8
#define SEQ 4096
#define MROWS (BATCH * SEQ)

typedef __bf16 bf16;
typedef __bf16 bf16x4 __attribute__((ext_vector_type(4)));
typedef __bf16 bf16x8 __attribute__((ext_vector_type(8)));
typedef float f32x4 __attribute__((ext_vector_type(4)));

#define CHUNK 16
#define BURN 80
#define NCHUNK (SEQ / CHUNK)   // 256 chunks per batch, 2048 chains

__device__ __forceinline__ bf16x8 cvt8(const f32x4 a, const f32x4 b) {
  bf16x8 h;
  h[0] = (bf16)a[0]; h[1] = (bf16)a[1]; h[2] = (bf16)a[2]; h[3] = (bf16)a[3];
  h[4] = (bf16)b[0]; h[5] = (bf16)b[1]; h[6] = (bf16)b[2]; h[7] = (bf16)b[3];
  return h;
}

// ================= k_pre: block 0 = dt/X/A_bar/XTs; blocks 1..16 CW; 17..32 WD ============
__global__ __launch_bounds__(256) void k_pre(
    const float* __restrict__ A, const float* __restrict__ C, const float* __restrict__ Dv,
    const float* __restrict__ log_dt, const float* __restrict__ W,
    float* __restrict__ A_bar, float* __restrict__ XTs,
    bf16* __restrict__ CW, bf16* __restrict__ WD) {
  __shared__ float Xs[32][32];
  const int bid = blockIdx.x, t = threadIdx.x;
  float* Xf = &Xs[0][0];

  if (bid == 0) {
    // dt partials + tree reduce (Xs as scratch)
    {
      float v0 = __expf(log_dt[t]);
      float v1 = __expf(log_dt[t + 256]);
      v0 = fminf(fmaxf(v0, 1e-4f), 1.0f);
      v1 = fminf(fmaxf(v1, 1e-4f), 1.0f);
      Xf[t] = v0 + v1;
    }
    __syncthreads();
    for (int s2 = 128; s2 > 0; s2 >>= 1) {
      if (t < s2) Xf[t] += Xf[t + s2];
      __syncthreads();
    }
    const float dtv = Xf[0] * (1.0f / 512.0f);
    __syncthreads();
    // stage M = I - 0.5dt*A
    {
      const int i0 = 4 * t;
      const f32x4 av = *(const f32x4*)(A + i0);
      f32x4 mv;
#pragma unroll
      for (int q = 0; q < 4; q++) {
        const int r = (i0 + q) >> 5, c = (i0 + q) & 31;
        mv[q] = (r == c ? 1.0f : 0.0f) - 0.5f * dtv * av[q];
      }
      *(f32x4*)(Xf + i0) = mv;
    }
    __syncthreads();
    // wave 0: X = M^{-1} by forward substitution (in-wave lockstep on Xs)
    if (t < 32) {
      const int j = t;
      float xcol[32];
#pragma unroll
      for (int i = 0; i < 32; i++) {
        float s0 = 0.f, s1 = 0.f, s2 = 0.f, s3 = 0.f;
#pragma unroll
        for (int k = 0; k < 32; k += 4) {
          if (k < i)     s0 -= Xf[i * 32 + k]     * xcol[k];
          if (k + 1 < i) s1 -= Xf[i * 32 + k + 1] * xcol[k + 1];
          if (k + 2 < i) s2 -= Xf[i * 32 + k + 2] * xcol[k + 2];
          if (k + 3 < i) s3 -= Xf[i * 32 + k + 3] * xcol[k + 3];
        }
        const float num = (i == j ? 1.0f : 0.0f) + ((s0 + s1) + (s2 + s3));
        xcol[i] = (i >= j) ? num / Xf[i * 32 + i] : 0.0f;
      }
#pragma unroll
      for (int i = 0; i < 32; i++) Xs[i][j] = xcol[i];
    }
    __syncthreads();
    // A_bar = (I + 0.5dt*A) @ X
    {
      const int i0 = 4 * t;
      const int r = t >> 3;
      f32x4 ov;
#pragma unroll
      for (int q = 0; q < 4; q++) {
        const int c = (i0 + q) & 31;
        float s = 0.f;
#pragma unroll
        for (int k = 0; k < 32; k++) {
          const float p2 = (r == k ? 1.0f : 0.0f) + 0.5f * dtv * A[r * 32 + k];
          s = fmaf(p2, Xf[k * 32 + c], s);
        }
        ov[q] = s;
      }
      *(f32x4*)(A_bar + i0) = ov;
    }
    // XTs[k][n] = dt * X[n][k]
#pragma unroll
    for (int i = 0; i < 4; i++) {
      const int idx = t + i * 256;
      const int k = idx >> 5, n = idx & 31;
      XTs[idx] = dtv * Xf[n * 32 + k];
    }
  } else if (bid <= 16) {
    // CW = W@C via direct-fragment MFMA (hi-bf16). Block owns 32 e-rows.
    const int w = t >> 6, lane = t & 63;
    const int l15 = lane & 15, kg = lane >> 4;
    const int m = w & 1, nf = w >> 1;
    const int eb = (bid - 1) * 32;
    const float* wp = W + (long)(eb + m * 16 + l15) * D_MODEL + kg * 8;
    const int ncol = nf * 16 + l15;
    f32x4 acc = (f32x4)(0.0f);
#pragma unroll 1
    for (int kt = 0; kt < 16; kt++) {
      const f32x4 w0 = *(const f32x4*)(wp + kt * 32);
      const f32x4 w1 = *(const f32x4*)(wp + kt * 32 + 4);
      const bf16x8 af = cvt8(w0, w1);
      bf16x8 bf;
#pragma unroll
      for (int j = 0; j < 8; j++)
        bf[j] = (bf16)C[(kt * 32 + kg * 8 + j) * D_STATE + ncol];
      acc = __builtin_amdgcn_mfma_f32_16x16x32_bf16(af, bf, acc, 0, 0, 0);
    }
#pragma unroll
    for (int jj = 0; jj < 4; jj++)
      CW[(eb + m * 16 + kg * 4 + jj) * D_STATE + ncol] = (bf16)acc[jj];
  } else {
    // WD = W * D
#pragma unroll
    for (int jj = 0; jj < 16; jj++) {
      const int i = (bid - 17) * 16384 + jj * 1024 + t * 4;
      const f32x4 wv = *(const f32x4*)(W + i);
      const f32x4 dv = *(const f32x4*)(Dv + (i & 511));
      bf16x4 h;
#pragma unroll
      for (int q = 0; q < 4; q++) h[q] = (bf16)(wv[q] * dv[q]);
      *(bf16x4*)(WD + i) = h;
    }
  }
}

// ================= k_uB: 512 blocks x 64 rows; pure streaming GEMM =================
// uB = (x @ B^T) @ XTs  +  xb emission. 2-deep explicit register pipeline.
__global__ __launch_bounds__(256, 2) void k_uB(
    const float* __restrict__ x, const float* __restrict__ B,
    const float* __restrict__ XTs,
    float* __restrict__ uB, bf16* __restrict__ xb) {
  __shared__ float sXT[1024];     // XTs copy (dt*X^T), 4 KB
  __shared__ float srw[64 * 33];  // s_raw transpose, 8.25 KB
  const int t = threadIdx.x, w = t >> 6, lane = t & 63;
  const int l15 = lane & 15, kg = lane >> 4;
  const long rowbase = (long)blockIdx.x * 64;

#pragma unroll
  for (int i = 0; i < 4; i++) sXT[t + i * 256] = XTs[t + i * 256];

  const int arow = w * 16 + l15;   // wave w owns rows [w*16, w*16+16)
  const float* xp = x + (rowbase + arow) * D_MODEL + kg * 8;
  bf16* xo = xb + (rowbase + arow) * D_MODEL + kg * 8;
  const float* bp0 = B + l15 * D_MODEL + kg * 8;
  const float* bp1 = B + (16 + l15) * D_MODEL + kg * 8;

  f32x4 acc0 = (f32x4)(0.0f), acc1 = (f32x4)(0.0f);
  f32x4 cx0, cx1, cb00, cb01, cb10, cb11;
  f32x4 nx0, nx1, nb00, nb01, nb10, nb11;
  cx0 = *(const f32x4*)(xp);      cx1 = *(const f32x4*)(xp + 4);
  cb00 = *(const f32x4*)(bp0);    cb01 = *(const f32x4*)(bp0 + 4);
  cb10 = *(const f32x4*)(bp1);    cb11 = *(const f32x4*)(bp1 + 4);

#pragma unroll 1
  for (int kt = 0; kt < 16; kt++) {
    if (kt < 15) {
      const int o = (kt + 1) * 32;
      nx0 = *(const f32x4*)(xp + o);    nx1 = *(const f32x4*)(xp + o + 4);
      nb00 = *(const f32x4*)(bp0 + o);  nb01 = *(const f32x4*)(bp0 + o + 4);
      nb10 = *(const f32x4*)(bp1 + o);  nb11 = *(const f32x4*)(bp1 + o + 4);
    }
    const bf16x8 af = cvt8(cx0, cx1);
    *(bf16x8*)(xo + kt * 32) = af;
    const bf16x8 bh0 = cvt8(cb00, cb01);
    const bf16x8 bh1 = cvt8(cb10, cb11);
    bf16x8 bl0, bl1;
#pragma unroll
    for (int q = 0; q < 4; q++) {
      bl0[q]     = (bf16)(cb00[q] - (float)bh0[q]);
      bl0[q + 4] = (bf16)(cb01[q] - (float)bh0[q + 4]);
      bl1[q]     = (bf16)(cb10[q] - (float)bh1[q]);
      bl1[q + 4] = (bf16)(cb11[q] - (float)bh1[q + 4]);
    }
    acc0 = __builtin_amdgcn_mfma_f32_16x16x32_bf16(af, bh0, acc0, 0, 0, 0);
    acc0 = __builtin_amdgcn_mfma_f32_16x16x32_bf16(af, bl0, acc0, 0, 0, 0);
    acc1 = __builtin_amdgcn_mfma_f32_16x16x32_bf16(af, bh1, acc1, 0, 0, 0);
    acc1 = __builtin_amdgcn_mfma_f32_16x16x32_bf16(af, bl1, acc1, 0, 0, 0);
    cx0 = nx0; cx1 = nx1;
    cb00 = nb00; cb01 = nb01; cb10 = nb10; cb11 = nb11;
  }
  // transpose accs into srw: row = w*16 + kg*4 + jj, col = l15 (+16 for acc1)
#pragma unroll
  for (int jj = 0; jj < 4; jj++) {
    srw[(w * 16 + kg * 4 + jj) * 33 + l15]      = acc0[jj];
    srw[(w * 16 + kg * 4 + jj) * 33 + 16 + l15] = acc1[jj];
  }
  __syncthreads();
  // uB[r][n] = sum_k srw[r][k] * sXT[k][n]   (srw: distinct banks across r; sXT: bank-spread broadcast)
  {
    const int r = t & 63, ng = t >> 6;          // ng in 0..3 -> cols [4ng,4ng+4) and +16
    f32x4 u0 = (f32x4)(0.0f), u1 = (f32x4)(0.0f);
#pragma unroll
    for (int k = 0; k < 32; k++) {
      const float sv = srw[r * 33 + k];
      const f32x4 x0 = *(const f32x4*)&sXT[k * 32 + ng * 4];
      const f32x4 x1 = *(const f32x4*)&sXT[k * 32 + ng * 4 + 16];
#pragma unroll
      for (int q = 0; q < 4; q++) {
        u0[q] = fmaf(sv, x0[q], u0[q]);
        u1[q] = fmaf(sv, x1[q], u1[q]);
      }
    }
    float* up = uB + (rowbase + r) * D_STATE;
    *(f32x4*)(up + ng * 4) = u0;
    *(f32x4*)(up + ng * 4 + 16) = u1;
  }
}

// ---------------- k_scan: standalone; a[] pinned in VGPRs (no remat/reload) ----------------
__global__ void k_scan(const float* __restrict__ uB, const float* __restrict__ A_bar,
                       bf16* __restrict__ Sb, float* __restrict__ fs) {
  __shared__ float sbuf[256];         // 8 groups x 32 state elems
  const int t = threadIdx.x;
  const int g = t >> 5, n = t & 31;
  const int chain = blockIdx.x * 8 + g;
  const int b = chain >> 8;           // 256 chunks per batch
  const int ch = chain & 255;
  const int cs = ch * CHUNK;
  const int t0 = cs - BURN;           // may be negative (u treated as 0 there)
  const int ce = cs + CHUNK;

  float a[32];
#pragma unroll
  for (int k = 0; k < 32; k += 4) {
    const f32x4 v = *(const f32x4*)(A_bar + n * 32 + k);
    a[k] = v[0]; a[k + 1] = v[1]; a[k + 2] = v[2]; a[k + 3] = v[3];
  }
#pragma unroll
  for (int k = 0; k < 32; k++) asm volatile("" : "+v"(a[k]));

  const float* ub = uB + (long)b * SEQ * D_STATE + n;
  bf16* sp = Sb + ((long)b * SEQ + cs) * D_STATE + n;
  float* myslot = &sbuf[g * 32];

  float s = 0.f;
  float ubuf[8], unext[8];
#pragma unroll
  for (int i = 0; i < 8; i++) {
    const int tt = t0 + i;
    ubuf[i] = (tt >= 0) ? ub[(long)tt * D_STATE] : 0.f;
  }
  for (int tg = t0; tg < ce; tg += 8) {
    const int tn = tg + 8;
#pragma unroll
    for (int i = 0; i < 8; i++) {
      const int tt = tn + i;
      unext[i] = (tt >= 0 && tt < ce) ? ub[(long)tt * D_STATE] : 0.f;
    }
#pragma unroll
    for (int i = 0; i < 8; i++) {
      const int tt = tg + i;
      myslot[n] = s;   // ds_write_b32, wave-ordered before the reads below
      const f32x4 s0 = *(const f32x4*)(myslot + 0);
      const f32x4 s1 = *(const f32x4*)(myslot + 4);
      const f32x4 s2 = *(const f32x4*)(myslot + 8);
      const f32x4 s3 = *(const f32x4*)(myslot + 12);
      const f32x4 s4 = *(const f32x4*)(myslot + 16);
      const f32x4 s5 = *(const f32x4*)(myslot + 20);
      const f32x4 s6 = *(const f32x4*)(myslot + 24);
      const f32x4 s7 = *(const f32x4*)(myslot + 28);
      float acc0 = ubuf[i], acc1 = 0.f, acc2 = 0.f, acc3 = 0.f;
#pragma unroll
      for (int q = 0; q < 4; q++) {
        acc0 = fmaf(a[0 + q],  s0[q], acc0);
        acc1 = fmaf(a[4 + q],  s1[q], acc1);
        acc2 = fmaf(a[8 + q],  s2[q], acc2);
        acc3 = fmaf(a[12 + q], s3[q], acc3);
        acc0 = fmaf(a[16 + q], s4[q], acc0);
        acc1 = fmaf(a[20 + q], s5[q], acc1);
        acc2 = fmaf(a[24 + q], s6[q], acc2);
        acc3 = fmaf(a[28 + q], s7[q], acc3);
      }
      const float z = (acc0 + acc1) + (acc2 + acc3);
      const float e = __expf(2.f * z);
      const float r = __builtin_amdgcn_rcpf(e + 1.f);
      s = fmaf(-2.f, r, 1.f);
      if (tt >= cs) sp[(long)(tt - cs) * D_STATE] = (bf16)s;
    }
#pragma unroll
    for (int i = 0; i < 8; i++) ubuf[i] = unext[i];
  }
  if (ch == NCHUNK - 1) fs[b * D_STATE + n] = s;
}

// ---------------- k_out: out = S@CW^T + xb@WD^T + b (bf16 MFMA, 128x128 tile) ----------------
__device__ __forceinline__ void stage_tile(const void* gbase, long row0, long rowStrideB,
                                           int kByte, void* lds, int w, int lane) {
#pragma unroll
  for (int j = 0; j < 2; j++) {
    const int base_off = (w << 11) + (j << 10);
    const int boff = base_off + (lane << 4);
    const int r = boff >> 6;
    const int s = (boff >> 4) & 3;
    const int cb = ((s ^ (r & 3)) << 4);
    const char* src = (const char*)gbase + (row0 + r) * rowStrideB + kByte + cb;
    __builtin_amdgcn_global_load_lds(
        (const __attribute__((address_space(1))) void*)src,
        (__attribute__((address_space(3))) void*)((char*)lds + base_off), 16, 0, 0);
  }
}

__global__ __launch_bounds__(256) void k_out(const bf16* __restrict__ xb,
                                             const bf16* __restrict__ WD,
                                             const bf16* __restrict__ Sb,
                                             const bf16* __restrict__ CW,
                                             const float* __restrict__ bias,
                                             float* __restrict__ out) {
  __shared__ bf16 As[2][128 * 32];
  __shared__ bf16 Bs[2][128 * 32];
  const int tid = threadIdx.x;
  const int w = tid >> 6, lane = tid & 63;
  const int swz = (blockIdx.x & 7) * 128 + (blockIdx.x >> 3);
  const int bm = swz >> 2, bn = swz & 3;
  const long rowbase = (long)bm * 128;
  const long colbase = (long)bn * 128;
  const int wr = w >> 1, wc = w & 1;
  const int l15 = lane & 15, kg = lane >> 4;
  const int kgs = kg ^ (l15 & 3);

  f32x4 acc[4][4];
#pragma unroll
  for (int m = 0; m < 4; m++)
#pragma unroll
    for (int n = 0; n < 4; n++) acc[m][n] = (f32x4)(0.0f);

  const int aoff = (wr * 64 + l15) * 32 + kgs * 8;
  const int boff = (wc * 64 + l15) * 32 + kgs * 8;

  auto STAGE = [&](int ti, int b) {
    if (ti < 16) {
      stage_tile(xb, rowbase, 1024, ti * 64, &As[b][0], w, lane);
      stage_tile(WD, colbase, 1024, ti * 64, &Bs[b][0], w, lane);
    } else {
      stage_tile(Sb, rowbase, 64, 0, &As[b][0], w, lane);
      stage_tile(CW, colbase, 64, 0, &Bs[b][0], w, lane);
    }
  };

  STAGE(0, 0);
  __syncthreads();
#pragma unroll 1
  for (int kt = 0; kt < 17; kt++) {
    const int cur = kt & 1;
    if (kt < 16) STAGE(kt + 1, cur ^ 1);
    bf16x8 af[4], bfr[4];
#pragma unroll
    for (int m = 0; m < 4; m++) af[m] = *(const bf16x8*)&As[cur][aoff + m * 16 * 32];
#pragma unroll
    for (int n = 0; n < 4; n++) bfr[n] = *(const bf16x8*)&Bs[cur][boff + n * 16 * 32];
#pragma unroll
    for (int m = 0; m < 4; m++)
#pragma unroll
      for (int n = 0; n < 4; n++)
        acc[m][n] = __builtin_amdgcn_mfma_f32_16x16x32_bf16(af[m], bfr[n], acc[m][n], 0, 0, 0);
    __syncthreads();
  }
#pragma unroll
  for (int n = 0; n < 4; n++) {
    const int e = (int)colbase + wc * 64 + n * 16 + l15;
    const float bv = bias[e];
#pragma unroll
    for (int m = 0; m < 4; m++) {
      const long r0 = rowbase + wr * 64 + m * 16 + kg * 4;
      const f32x4 v = acc[m][n];
#pragma unroll
      for (int jj = 0; jj < 4; jj++) out[(r0 + jj) * (long)D_MODEL + e] = v[jj] + bv;
    }
  }
}

extern "C" void kernel_launch(void* const* d_in, const int* in_sizes, int n_in,
                              void* d_out, int out_size, void* d_ws, size_t ws_size,
                              hipStream_t stream) {
  const float* x      = (const float*)d_in[0];
  const float* A      = (const float*)d_in[1];
  const float* B      = (const float*)d_in[2];
  const float* C      = (const float*)d_in[3];
  const float* Dv     = (const float*)d_in[4];
  const float* log_dt = (const float*)d_in[5];
  const float* W      = (const float*)d_in[6];
  const float* b_out  = (const float*)d_in[7];
  float* out = (float*)d_out;
  float* fs  = out + (long)MROWS * D_MODEL;  // final_state (8x32) after y

  char* ws = (char*)d_ws;
  float* A_bar = (float*)(ws + 0);                    // 4 KB
  float* XTs   = (float*)(ws + (4L << 10));           // 4 KB (dt * X^T)
  bf16*  CW    = (bf16*)(ws + (68L << 10));           // 32 KB
  bf16*  WD    = (bf16*)(ws + (100L << 10));          // 512 KB
  bf16*  Sb    = (bf16*)(ws + (612L << 10));          // 2 MB
  float* uB    = (float*)(ws + (2660L << 10));        // 4 MB
  bf16*  xb    = (bf16*)(ws + (6756L << 10));         // 32 MB

  k_pre<<<dim3(33), dim3(256), 0, stream>>>(A, C, Dv, log_dt, W, A_bar, XTs, CW, WD);
  k_uB<<<dim3(MROWS / 64), dim3(256), 0, stream>>>(x, B, XTs, uB, xb);
  k_scan<<<dim3(256), dim3(256), 0, stream>>>(uB, A_bar, Sb, fs);
  k_out<<<dim3((MROWS / 128) * (D_MODEL / 128)), dim3(256), 0, stream>>>(xb, WD, Sb, CW, b_out, out);
}